// Round 12
// baseline (81.953 us; speedup 1.0000x reference)
//
#include <hip/hip_runtime.h>

#define L_SEQ 32768
#define NDIM 256
#define HDIM 256
#define NCAT 512    // 2*NDIM (re/im interleaved)
#define LC 32       // scan chunk length
#define NCHUNK 1024 // L_SEQ / LC

typedef unsigned short u16;
typedef unsigned int u32;
typedef __bf16 bf16x8 __attribute__((ext_vector_type(8)));
typedef float f32x4 __attribute__((ext_vector_type(4)));
typedef __attribute__((address_space(3))) void lds_void;
typedef const __attribute__((address_space(1))) void gbl_void;

__device__ __forceinline__ u16 f2bf(float f) {
  u32 u = __builtin_bit_cast(u32, f);
  u = u + 0x7fffu + ((u >> 16) & 1u);
  return (u16)(u >> 16);
}
__device__ __forceinline__ float bf2f(u16 v) {
  u32 u = ((u32)v) << 16;
  return __builtin_bit_cast(float, u);
}

// ---------------------------------------------------------------------------
// PREP (R11-verified): x -> bf16 pre-swizzled; Bcat pre-swizzled (BK=64 read);
// Ccat pre-swizzled (BK=32 read); lambda and lambda^LC tables.
// ---------------------------------------------------------------------------
__global__ __launch_bounds__(256) void prep_kernel(
    const float* __restrict__ x,
    const float* __restrict__ nu_log, const float* __restrict__ theta_log,
    const float* __restrict__ B_re, const float* __restrict__ B_im,
    const float* __restrict__ C_re, const float* __restrict__ C_im,
    const float* __restrict__ gamma_log,
    u16* __restrict__ x_bf, u16* __restrict__ Bcat, u16* __restrict__ Ccat,
    float2* __restrict__ lam, float2* __restrict__ lamLC)
{
  const int blk = blockIdx.x, tid = threadIdx.x;
  if (blk < 2048) {
    const float4* src = (const float4*)x;
#pragma unroll
    for (int j = 0; j < 4; ++j) {
      int i = blk * 1024 + j * 256 + tid;
      int r = i >> 6;
      int col = (i & 63) * 4;
      float4 v = src[i];
      int pcol = col ^ ((r & 7) << 3);
      *(ushort4*)(x_bf + (size_t)r * 256 + pcol) =
          make_ushort4(f2bf(v.x), f2bf(v.y), f2bf(v.z), f2bf(v.w));
    }
  } else if (blk < 2560) {
    int pr = blk - 2048;
    int jj = pr >> 1, p = pr & 1;
    float g = expf(gamma_log[jj]);
    const float* src = (p ? B_im : B_re) + (size_t)jj * HDIM;
    int lc = tid ^ ((pr & 7) << 3);
    Bcat[(size_t)pr * HDIM + tid] = f2bf(src[lc] * g);
  } else if (blk < 2816) {
    int ph = blk - 2560;
    int lr = ph ^ ((ph >> 2) & 1);
#pragma unroll
    for (int half = 0; half < 2; ++half) {
      int pcol = half * 256 + tid;
      int kt = pcol >> 5, w = pcol & 31, pc = w >> 3, e = w & 7;
      int lc2 = kt * 32 + (pc ^ (lr & 3)) * 8 + e;
      int jj = lc2 >> 1, p = lc2 & 1;
      float v = p ? -C_im[(size_t)lr * NDIM + jj] : C_re[(size_t)lr * NDIM + jj];
      Ccat[(size_t)ph * NCAT + pcol] = f2bf(v);
    }
  } else {
    float nu_e = expf(nu_log[tid]);
    float th = expf(theta_log[tid]);
    float r = expf(-nu_e);
    lam[tid] = make_float2(r * cosf(th), r * sinf(th));
    float rL = expf(-(float)LC * nu_e);
    float ph = (float)LC * th;
    lamLC[tid] = make_float2(rL * cosf(ph), rL * sinf(ph));
  }
}

// ---------------------------------------------------------------------------
// GEMM1 (R11-verified, UNCHANGED): BK=64, pre-swizzled operands.
// ---------------------------------------------------------------------------
__global__ __launch_bounds__(256) void gemm1_kernel(
    const u16* __restrict__ A,   // M x K bf16 (cols pre-swizzled per row)
    const u16* __restrict__ Bm,  // N x K bf16 (cols pre-swizzled per row)
    u16* __restrict__ Cout,      // M x N bf16
    int M, int N, int K)
{
  constexpr int BM = 128, BN = 128, BK = 64;
  __shared__ u16 lA[BM * BK];
  __shared__ u16 lB[BN * BK];
  const int tid = threadIdx.x;
  const int lane = tid & 63, wave = tid >> 6;
  const int bn = blockIdx.x, bm = blockIdx.y;
  const int row0 = bm * BM, col0 = bn * BN;
  const int wm = (wave >> 1) * 64, wn = (wave & 1) * 64;
  const int fr = lane & 15, fq = lane >> 4;
  const int swz = (fr & 7) << 4;
  const char* lab = (const char*)lA;
  const char* lbb = (const char*)lB;

  f32x4 acc[4][4] = {};
  const int nkt = K / BK;  // 4
  for (int kt = 0; kt < nkt; ++kt) {
    const int k0 = kt * BK;
#pragma unroll
    for (int j = 0; j < 4; ++j) {
      int c = j * 256 + tid;
      int r = c >> 3, b = c & 7;
      const u16* ga = A + (size_t)(row0 + r) * K + (k0 + b * 8);
      const u16* gb = Bm + (size_t)(col0 + r) * K + (k0 + b * 8);
      __builtin_amdgcn_global_load_lds((gbl_void*)ga, (lds_void*)&lA[c * 8], 16, 0, 0);
      __builtin_amdgcn_global_load_lds((gbl_void*)gb, (lds_void*)&lB[c * 8], 16, 0, 0);
    }
    __syncthreads();

#pragma unroll
    for (int h = 0; h < 2; ++h) {
      bf16x8 af[4], bfr[4];
      const int ko = (h * 64 + fq * 16) ^ swz;
#pragma unroll
      for (int i = 0; i < 4; ++i) {
        af[i]  = *(const bf16x8*)(lab + (wm + i * 16 + fr) * 128 + ko);
        bfr[i] = *(const bf16x8*)(lbb + (wn + i * 16 + fr) * 128 + ko);
      }
#pragma unroll
      for (int i = 0; i < 4; ++i)
#pragma unroll
        for (int j = 0; j < 4; ++j)
          acc[i][j] = __builtin_amdgcn_mfma_f32_16x16x32_bf16(af[i], bfr[j], acc[i][j], 0, 0, 0);
    }
    __syncthreads();
  }

  const int fq2 = lane >> 4;
#pragma unroll
  for (int i = 0; i < 4; ++i)
#pragma unroll
    for (int j = 0; j < 4; ++j) {
      int cg = col0 + wn + j * 16 + fr;
#pragma unroll
      for (int r = 0; r < 4; ++r) {
        int rg = row0 + wm + i * 16 + fq2 * 4 + r;
        Cout[(size_t)rg * N + cg] = f2bf(acc[i][j][r]);
      }
    }
}

// ---------------------------------------------------------------------------
// Scan phase 1 (verified, LC=32): per-chunk final state over bf16 Bu
// ---------------------------------------------------------------------------
__global__ __launch_bounds__(256) void scan_carry_kernel(
    const ushort2* __restrict__ Bu2, const float2* __restrict__ lam,
    float2* __restrict__ carry)
{
  const int n = threadIdx.x, b = blockIdx.x;
  const float2 la = lam[n];
  float sre = 0.f, sim = 0.f;
  const ushort2* p = Bu2 + (size_t)b * LC * NDIM + n;
#pragma unroll 8
  for (int j = 0; j < LC; ++j) {
    ushort2 bu = p[(size_t)j * NDIM];
    float bre = bf2f(bu.x), bim = bf2f(bu.y);
    float nre = la.x * sre - la.y * sim + bre;
    float nim = la.x * sim + la.y * sre + bim;
    sre = nre; sim = nim;
  }
  carry[(size_t)b * NDIM + n] = make_float2(sre, sim);
}

// ---------------------------------------------------------------------------
// Scan phase 2 (verified pattern, 1024 chunks): Hillis-Steele in LDS.
// ---------------------------------------------------------------------------
__global__ __launch_bounds__(1024) void carry_scan_kernel(
    const float2* __restrict__ carry, const float2* __restrict__ lamLC,
    float2* __restrict__ corr)
{
  __shared__ float4 e[NCHUNK];
  const int n = blockIdx.x;
  const int b = threadIdx.x;
  float2 a = lamLC[n];
  float2 v = carry[(size_t)b * NDIM + n];
  e[b] = make_float4(a.x, a.y, v.x, v.y);
  __syncthreads();
#pragma unroll
  for (int d = 1; d < NCHUNK; d <<= 1) {
    float4 prev;
    if (b >= d) prev = e[b - d];
    __syncthreads();
    if (b >= d) {
      float2 ap = make_float2(prev.x, prev.y), vp = make_float2(prev.z, prev.w);
      float2 na, nv;
      na.x = a.x * ap.x - a.y * ap.y;
      na.y = a.x * ap.y + a.y * ap.x;
      nv.x = a.x * vp.x - a.y * vp.y + v.x;
      nv.y = a.x * vp.y + a.y * vp.x + v.y;
      a = na; v = nv;
      e[b] = make_float4(a.x, a.y, v.x, v.y);
    }
    __syncthreads();
  }
  if (b == 0) corr[n] = make_float2(0.f, 0.f);
  if (b < NCHUNK - 1) corr[(size_t)(b + 1) * NDIM + n] = v;
}

// ---------------------------------------------------------------------------
// GEMM2 fused, BM=32 (one block = one 32-row chunk x 256 cols, 4 waves,
// 32x64 per wave). LDS 48KB -> 3 blocks/CU (was 80KB -> 2). Same verified
// stage/scan/k-loop/epilogue forms, mechanically resized.
// ---------------------------------------------------------------------------
__global__ __launch_bounds__(256, 3) void gemm2_kernel(
    const u16* __restrict__ Bu,   // L x 512 bf16
    const u16* __restrict__ Cc,   // 256 x 512 bf16 (pre-swizzled)
    const float2* __restrict__ lam,
    const float2* __restrict__ corr,
    const u16* __restrict__ xbf,  // L x 256 bf16 (pre-swizzled cols)
    const float* __restrict__ Dv,
    float* __restrict__ out)      // L x 256 f32
{
  constexpr int BM = 32, BK = 32, K = NCAT; // 16 k-steps
  __shared__ u16 sT[BM * K];      // 32KB: Bu chunk -> (swizzled) s tile
  __shared__ u16 lB1[256 * BK];   // 16KB Ccat slice
  const int tid = threadIdx.x;
  const int lane = tid & 63, wave = tid >> 6;
  const int bm = blockIdx.x;
  const int row0 = bm * BM;
  const int wn = wave * 64;
  const int fr = lane & 15, fq = lane >> 4;
  char* sb = (char*)sT;
  const char* cbB = (const char*)lB1;

  // stage Bu chunk linear (2048 x 16B) + Ccat slice kt=0 (1024 x 16B)
#pragma unroll
  for (int j = 0; j < 8; ++j) {
    int q = j * 256 + tid;
    int row = q >> 6, off = q & 63;
    const u16* g = Bu + (size_t)(row0 + row) * NCAT + off * 8;
    __builtin_amdgcn_global_load_lds((gbl_void*)g, (lds_void*)&sT[q * 8], 16, 0, 0);
  }
#pragma unroll
  for (int j = 0; j < 4; ++j) {
    int q = j * 256 + tid;
    int row = q >> 2, c = q & 3;
    const u16* g = Cc + (size_t)row * K + c * 8;
    __builtin_amdgcn_global_load_lds((gbl_void*)g, (lds_void*)&lB1[q * 8], 16, 0, 0);
  }
  float2 la = lam[tid];
  float2 c0 = corr[(size_t)bm * NDIM + tid];
  __syncthreads();

  // in-place scan over 32 rows (verified form): read linear, write swizzled
  {
    float sre = c0.x, sim = c0.y;
    ushort2 buf[8], nbuf[8];
    const int lb = tid * 4;
#pragma unroll
    for (int s = 0; s < 8; ++s) buf[s] = *(const ushort2*)(sb + s * 1024 + lb);
#pragma unroll
    for (int b8 = 0; b8 < 4; ++b8) {
      if (b8 < 3) {
#pragma unroll
        for (int s = 0; s < 8; ++s)
          nbuf[s] = *(const ushort2*)(sb + (b8 * 8 + 8 + s) * 1024 + lb);
      }
#pragma unroll
      for (int s = 0; s < 8; ++s) {
        int row = b8 * 8 + s;
        float bre = bf2f(buf[s].x), bim = bf2f(buf[s].y);
        float nre = la.x * sre - la.y * sim + bre;
        float nim = la.x * sim + la.y * sre + bim;
        sre = nre; sim = nim;
        *(ushort2*)(sb + row * 1024 + (lb ^ ((row & 7) << 4))) =
            make_ushort2(f2bf(sre), f2bf(sim));
      }
#pragma unroll
      for (int s = 0; s < 8; ++s) buf[s] = nbuf[s];
    }
  }
  __syncthreads();

  // MFMA: 16 k-steps, reg-prefetch pipeline (verified form), af[2] now
  f32x4 acc[2][4] = {};
#pragma unroll 1
  for (int kt = 0; kt < 16; ++kt) {
    bf16x8 af[2], bfr[4];
#pragma unroll
    for (int j = 0; j < 4; ++j) {
      int rowb = wn + j * 16 + fr;
      bfr[j] = *(const bf16x8*)(cbB + ((rowb * 64 + fq * 16) ^ ((rowb & 7) << 4)));
    }
#pragma unroll
    for (int i = 0; i < 2; ++i) {
      int row = i * 16 + fr;
      int wb = kt * 64 + fq * 16;
      af[i] = *(const bf16x8*)(sb + row * 1024 + (wb ^ ((row & 7) << 4)));
    }
    __syncthreads();
    __builtin_amdgcn_sched_barrier(0);
    if (kt < 15) {
#pragma unroll
      for (int j = 0; j < 4; ++j) {
        int q = j * 256 + tid;
        int row = q >> 2, c = q & 3;
        const u16* g = Cc + (size_t)row * K + (kt + 1) * BK + c * 8;
        __builtin_amdgcn_global_load_lds((gbl_void*)g, (lds_void*)&lB1[q * 8], 16, 0, 0);
      }
    }
    __builtin_amdgcn_sched_barrier(0);
#pragma unroll
    for (int i = 0; i < 2; ++i)
#pragma unroll
      for (int j = 0; j < 4; ++j)
        acc[i][j] = __builtin_amdgcn_mfma_f32_16x16x32_bf16(af[i], bfr[j], acc[i][j], 0, 0, 0);
    __syncthreads();
  }

  // epilogue: y = acc + x*D (xbf cols pre-swizzled: c -> c ^ ((r&7)<<3))
#pragma unroll
  for (int i = 0; i < 2; ++i)
#pragma unroll
    for (int j = 0; j < 4; ++j) {
      int cg = wn + j * 16 + fr;
      float dvc = Dv[cg];
#pragma unroll
      for (int r = 0; r < 4; ++r) {
        int rg = row0 + i * 16 + fq * 4 + r;
        float v = acc[i][j][r] +
                  bf2f(xbf[(size_t)rg * HDIM + (cg ^ ((rg & 7) << 3))]) * dvc;
        out[(size_t)rg * HDIM + cg] = v;
      }
    }
}

// ---------------------------------------------------------------------------
extern "C" void kernel_launch(void* const* d_in, const int* in_sizes, int n_in,
                              void* d_out, int out_size, void* d_ws, size_t ws_size,
                              hipStream_t stream)
{
  (void)in_sizes; (void)n_in; (void)out_size; (void)ws_size;
  const float* x         = (const float*)d_in[0];
  const float* nu_log    = (const float*)d_in[1];
  const float* theta_log = (const float*)d_in[2];
  const float* B_re      = (const float*)d_in[3];
  const float* B_im      = (const float*)d_in[4];
  const float* C_re      = (const float*)d_in[5];
  const float* C_im      = (const float*)d_in[6];
  const float* Dv        = (const float*)d_in[7];
  const float* gamma_log = (const float*)d_in[8];

  char* ws = (char*)d_ws;
  u16*    x_bf  = (u16*)ws;                                  // 16 MB
  u16*    Bu_bf = (u16*)(ws + ((size_t)16 << 20));           // 32 MB
  u16*    Bcat  = (u16*)(ws + ((size_t)48 << 20));           // 256 KB
  u16*    Ccat  = (u16*)(ws + ((size_t)48 << 20) + 262144);  // 256 KB
  float2* lam   = (float2*)(ws + ((size_t)48 << 20) + 524288);
  float2* lamLC = (float2*)(ws + ((size_t)48 << 20) + 524288 + 4096);
  float2* carry = (float2*)(ws + ((size_t)49 << 20));        // 2 MB
  float2* corr  = (float2*)(ws + ((size_t)52 << 20));        // 2 MB

  prep_kernel<<<2817, 256, 0, stream>>>(x, nu_log, theta_log, B_re, B_im,
                                        C_re, C_im, gamma_log,
                                        x_bf, Bcat, Ccat, lam, lamLC);

  gemm1_kernel<<<dim3(NCAT / 128, L_SEQ / 128), 256, 0, stream>>>(
      x_bf, Bcat, Bu_bf, L_SEQ, NCAT, HDIM);

  scan_carry_kernel<<<NCHUNK, 256, 0, stream>>>((const ushort2*)Bu_bf, lam, carry);

  carry_scan_kernel<<<NDIM, 1024, 0, stream>>>(carry, lamLC, corr);

  gemm2_kernel<<<NCHUNK, 256, 0, stream>>>(
      Bu_bf, Ccat, lam, corr, x_bf, Dv, (float*)d_out);
}

// Round 13
// 75.678 us; speedup vs baseline: 1.0829x; 1.0829x over previous
//
#include <hip/hip_runtime.h>

#define L_SEQ 32768
#define NDIM 256
#define HDIM 256
#define NCAT 512   // 2*NDIM (re/im interleaved)
#define LC 64      // scan chunk length
#define NCHUNK 512 // L_SEQ / LC

typedef unsigned short u16;
typedef unsigned int u32;
typedef __bf16 bf16x8 __attribute__((ext_vector_type(8)));
typedef float f32x4 __attribute__((ext_vector_type(4)));
typedef __attribute__((address_space(3))) void lds_void;
typedef const __attribute__((address_space(1))) void gbl_void;

__device__ __forceinline__ u16 f2bf(float f) {
  u32 u = __builtin_bit_cast(u32, f);
  u = u + 0x7fffu + ((u >> 16) & 1u);
  return (u16)(u >> 16);
}
__device__ __forceinline__ float bf2f(u16 v) {
  u32 u = ((u32)v) << 16;
  return __builtin_bit_cast(float, u);
}

// ---------------------------------------------------------------------------
// PREP: x -> bf16 pre-swizzled (R11); Bcat pre-swizzled (R11, BK=64 read);
// Ccat PLAIN row-major (consumed directly from L2 in gemm2); lambda tables.
// ---------------------------------------------------------------------------
__global__ __launch_bounds__(256) void prep_kernel(
    const float* __restrict__ x,
    const float* __restrict__ nu_log, const float* __restrict__ theta_log,
    const float* __restrict__ B_re, const float* __restrict__ B_im,
    const float* __restrict__ C_re, const float* __restrict__ C_im,
    const float* __restrict__ gamma_log,
    u16* __restrict__ x_bf, u16* __restrict__ Bcat, u16* __restrict__ Ccat,
    float2* __restrict__ lam, float2* __restrict__ lamLC)
{
  const int blk = blockIdx.x, tid = threadIdx.x;
  if (blk < 2048) {
    const float4* src = (const float4*)x;
#pragma unroll
    for (int j = 0; j < 4; ++j) {
      int i = blk * 1024 + j * 256 + tid;
      int r = i >> 6;
      int col = (i & 63) * 4;
      float4 v = src[i];
      int pcol = col ^ ((r & 7) << 3);
      *(ushort4*)(x_bf + (size_t)r * 256 + pcol) =
          make_ushort4(f2bf(v.x), f2bf(v.y), f2bf(v.z), f2bf(v.w));
    }
  } else if (blk < 2560) {
    int pr = blk - 2048;
    int jj = pr >> 1, p = pr & 1;
    float g = expf(gamma_log[jj]);
    const float* src = (p ? B_im : B_re) + (size_t)jj * HDIM;
    int lc = tid ^ ((pr & 7) << 3);
    Bcat[(size_t)pr * HDIM + tid] = f2bf(src[lc] * g);
  } else if (blk < 2816) {
    // Ccat row h (PLAIN): col 2j = C_re[h][j], col 2j+1 = -C_im[h][j]
    int h = blk - 2560;
#pragma unroll
    for (int half = 0; half < 2; ++half) {
      int nc = half * 256 + tid;
      int jj = nc >> 1, p = nc & 1;
      float v = p ? -C_im[(size_t)h * NDIM + jj] : C_re[(size_t)h * NDIM + jj];
      Ccat[(size_t)h * NCAT + nc] = f2bf(v);
    }
  } else {
    float nu_e = expf(nu_log[tid]);
    float th = expf(theta_log[tid]);
    float r = expf(-nu_e);
    lam[tid] = make_float2(r * cosf(th), r * sinf(th));
    float rL = expf(-(float)LC * nu_e);
    float ph = (float)LC * th;
    lamLC[tid] = make_float2(rL * cosf(ph), rL * sinf(ph));
  }
}

// ---------------------------------------------------------------------------
// GEMM1 (R11-verified, UNCHANGED): BK=64, pre-swizzled operands.
// ---------------------------------------------------------------------------
__global__ __launch_bounds__(256) void gemm1_kernel(
    const u16* __restrict__ A,   // M x K bf16 (cols pre-swizzled per row)
    const u16* __restrict__ Bm,  // N x K bf16 (cols pre-swizzled per row)
    u16* __restrict__ Cout,      // M x N bf16
    int M, int N, int K)
{
  constexpr int BM = 128, BN = 128, BK = 64;
  __shared__ u16 lA[BM * BK];
  __shared__ u16 lB[BN * BK];
  const int tid = threadIdx.x;
  const int lane = tid & 63, wave = tid >> 6;
  const int bn = blockIdx.x, bm = blockIdx.y;
  const int row0 = bm * BM, col0 = bn * BN;
  const int wm = (wave >> 1) * 64, wn = (wave & 1) * 64;
  const int fr = lane & 15, fq = lane >> 4;
  const int swz = (fr & 7) << 4;
  const char* lab = (const char*)lA;
  const char* lbb = (const char*)lB;

  f32x4 acc[4][4] = {};
  const int nkt = K / BK;  // 4
  for (int kt = 0; kt < nkt; ++kt) {
    const int k0 = kt * BK;
#pragma unroll
    for (int j = 0; j < 4; ++j) {
      int c = j * 256 + tid;
      int r = c >> 3, b = c & 7;
      const u16* ga = A + (size_t)(row0 + r) * K + (k0 + b * 8);
      const u16* gb = Bm + (size_t)(col0 + r) * K + (k0 + b * 8);
      __builtin_amdgcn_global_load_lds((gbl_void*)ga, (lds_void*)&lA[c * 8], 16, 0, 0);
      __builtin_amdgcn_global_load_lds((gbl_void*)gb, (lds_void*)&lB[c * 8], 16, 0, 0);
    }
    __syncthreads();

#pragma unroll
    for (int h = 0; h < 2; ++h) {
      bf16x8 af[4], bfr[4];
      const int ko = (h * 64 + fq * 16) ^ swz;
#pragma unroll
      for (int i = 0; i < 4; ++i) {
        af[i]  = *(const bf16x8*)(lab + (wm + i * 16 + fr) * 128 + ko);
        bfr[i] = *(const bf16x8*)(lbb + (wn + i * 16 + fr) * 128 + ko);
      }
#pragma unroll
      for (int i = 0; i < 4; ++i)
#pragma unroll
        for (int j = 0; j < 4; ++j)
          acc[i][j] = __builtin_amdgcn_mfma_f32_16x16x32_bf16(af[i], bfr[j], acc[i][j], 0, 0, 0);
    }
    __syncthreads();
  }

  const int fq2 = lane >> 4;
#pragma unroll
  for (int i = 0; i < 4; ++i)
#pragma unroll
    for (int j = 0; j < 4; ++j) {
      int cg = col0 + wn + j * 16 + fr;
#pragma unroll
      for (int r = 0; r < 4; ++r) {
        int rg = row0 + wm + i * 16 + fq2 * 4 + r;
        Cout[(size_t)rg * N + cg] = f2bf(acc[i][j][r]);
      }
    }
}

// ---------------------------------------------------------------------------
// Scan phase 1 (verified): per-chunk final state over bf16 Bu
// ---------------------------------------------------------------------------
__global__ __launch_bounds__(256) void scan_carry_kernel(
    const ushort2* __restrict__ Bu2, const float2* __restrict__ lam,
    float2* __restrict__ carry)
{
  const int n = threadIdx.x, b = blockIdx.x;
  const float2 la = lam[n];
  float sre = 0.f, sim = 0.f;
  const ushort2* p = Bu2 + (size_t)b * LC * NDIM + n;
#pragma unroll 8
  for (int j = 0; j < LC; ++j) {
    ushort2 bu = p[(size_t)j * NDIM];
    float bre = bf2f(bu.x), bim = bf2f(bu.y);
    float nre = la.x * sre - la.y * sim + bre;
    float nim = la.x * sim + la.y * sre + bim;
    sre = nre; sim = nim;
  }
  carry[(size_t)b * NDIM + n] = make_float2(sre, sim);
}

// ---------------------------------------------------------------------------
// Scan phase 2 (verified): log-depth Hillis-Steele in LDS.
// ---------------------------------------------------------------------------
__global__ __launch_bounds__(512) void carry_scan_kernel(
    const float2* __restrict__ carry, const float2* __restrict__ lamLC,
    float2* __restrict__ corr)
{
  __shared__ float4 e[NCHUNK];
  const int n = blockIdx.x;
  const int b = threadIdx.x;
  float2 a = lamLC[n];
  float2 v = carry[(size_t)b * NDIM + n];
  e[b] = make_float4(a.x, a.y, v.x, v.y);
  __syncthreads();
#pragma unroll
  for (int d = 1; d < NCHUNK; d <<= 1) {
    float4 prev;
    if (b >= d) prev = e[b - d];
    __syncthreads();
    if (b >= d) {
      float2 ap = make_float2(prev.x, prev.y), vp = make_float2(prev.z, prev.w);
      float2 na, nv;
      na.x = a.x * ap.x - a.y * ap.y;
      na.y = a.x * ap.y + a.y * ap.x;
      nv.x = a.x * vp.x - a.y * vp.y + v.x;
      nv.y = a.x * vp.y + a.y * vp.x + v.y;
      a = na; v = nv;
      e[b] = make_float4(a.x, a.y, v.x, v.y);
    }
    __syncthreads();
  }
  if (b == 0) corr[n] = make_float2(0.f, 0.f);
  if (b < NCHUNK - 1) corr[(size_t)(b + 1) * NDIM + n] = v;
}

// ---------------------------------------------------------------------------
// GEMM2 fused: one block = one chunk (64 rows) x 256 cols, 4 waves, 64x64
// per wave. Stage Bu -> in-place scan -> BARRIER-FREE k-loop: bfr read
// DIRECTLY from L2-resident Ccat into VGPRs (no lB1, no k-loop barriers);
// af from swizzled sT. Values bit-identical to R11 -> absmax canary 0.0625.
// ---------------------------------------------------------------------------
__global__ __launch_bounds__(256, 2) void gemm2_kernel(
    const u16* __restrict__ Bu,   // L x 512 bf16
    const u16* __restrict__ Cc,   // 256 x 512 bf16 (plain)
    const float2* __restrict__ lam,
    const float2* __restrict__ corr,
    const u16* __restrict__ xbf,  // L x 256 bf16 (pre-swizzled cols)
    const float* __restrict__ Dv,
    float* __restrict__ out)      // L x 256 f32
{
  constexpr int BM = 64, K = NCAT; // 16 k-steps of 32
  __shared__ u16 sT[BM * K];      // 64KB: Bu tile -> (swizzled) s tile
  const int tid = threadIdx.x;
  const int lane = tid & 63, wave = tid >> 6;
  const int bm = blockIdx.x;
  const int row0 = bm * BM;
  const int wn = wave * 64;
  const int fr = lane & 15, fq = lane >> 4;
  char* sb = (char*)sT;

  // stage Bu tile linear (4096 x 16B)
#pragma unroll
  for (int j = 0; j < 16; ++j) {
    int q = j * 256 + tid;
    int row = q >> 6, off = q & 63;
    const u16* g = Bu + (size_t)(row0 + row) * NCAT + off * 8;
    __builtin_amdgcn_global_load_lds((gbl_void*)g, (lds_void*)&sT[q * 8], 16, 0, 0);
  }
  float2 la = lam[tid];
  float2 c0 = corr[(size_t)bm * NDIM + tid];
  __syncthreads();

  // in-place scan (verified): read linear, write swizzled
  {
    float sre = c0.x, sim = c0.y;
    ushort2 buf[8], nbuf[8];
    const int lb = tid * 4;
#pragma unroll
    for (int s = 0; s < 8; ++s) buf[s] = *(const ushort2*)(sb + s * 1024 + lb);
#pragma unroll
    for (int b8 = 0; b8 < 8; ++b8) {
      if (b8 < 7) {
#pragma unroll
        for (int s = 0; s < 8; ++s)
          nbuf[s] = *(const ushort2*)(sb + (b8 * 8 + 8 + s) * 1024 + lb);
      }
#pragma unroll
      for (int s = 0; s < 8; ++s) {
        int row = b8 * 8 + s;
        float bre = bf2f(buf[s].x), bim = bf2f(buf[s].y);
        float nre = la.x * sre - la.y * sim + bre;
        float nim = la.x * sim + la.y * sre + bim;
        sre = nre; sim = nim;
        *(ushort2*)(sb + row * 1024 + (lb ^ ((row & 7) << 4))) =
            make_ushort2(f2bf(sre), f2bf(sim));
      }
#pragma unroll
      for (int s = 0; s < 8; ++s) buf[s] = nbuf[s];
    }
  }
  __syncthreads();

  // k-loop: NO barriers. bfr direct from global (L2), af from LDS.
  f32x4 acc[4][4] = {};
#pragma unroll 2
  for (int kt = 0; kt < 16; ++kt) {
    bf16x8 af[4], bfr[4];
#pragma unroll
    for (int j = 0; j < 4; ++j)
      bfr[j] = *(const bf16x8*)(Cc + (size_t)(wn + j * 16 + fr) * K + kt * 32 + fq * 8);
#pragma unroll
    for (int i = 0; i < 4; ++i) {
      int row = i * 16 + fr;
      int wb = kt * 64 + fq * 16;
      af[i] = *(const bf16x8*)(sb + row * 1024 + (wb ^ ((row & 7) << 4)));
    }
#pragma unroll
    for (int i = 0; i < 4; ++i)
#pragma unroll
      for (int j = 0; j < 4; ++j)
        acc[i][j] = __builtin_amdgcn_mfma_f32_16x16x32_bf16(af[i], bfr[j], acc[i][j], 0, 0, 0);
  }

  // epilogue: y = acc + x*D (xbf cols pre-swizzled: c -> c ^ ((r&7)<<3))
#pragma unroll
  for (int i = 0; i < 4; ++i)
#pragma unroll
    for (int j = 0; j < 4; ++j) {
      int cg = wn + j * 16 + fr;
      float dvc = Dv[cg];
#pragma unroll
      for (int r = 0; r < 4; ++r) {
        int rg = row0 + i * 16 + fq * 4 + r;
        float v = acc[i][j][r] +
                  bf2f(xbf[(size_t)rg * HDIM + (cg ^ ((rg & 7) << 3))]) * dvc;
        out[(size_t)rg * HDIM + cg] = v;
      }
    }
}

// ---------------------------------------------------------------------------
extern "C" void kernel_launch(void* const* d_in, const int* in_sizes, int n_in,
                              void* d_out, int out_size, void* d_ws, size_t ws_size,
                              hipStream_t stream)
{
  (void)in_sizes; (void)n_in; (void)out_size; (void)ws_size;
  const float* x         = (const float*)d_in[0];
  const float* nu_log    = (const float*)d_in[1];
  const float* theta_log = (const float*)d_in[2];
  const float* B_re      = (const float*)d_in[3];
  const float* B_im      = (const float*)d_in[4];
  const float* C_re      = (const float*)d_in[5];
  const float* C_im      = (const float*)d_in[6];
  const float* Dv        = (const float*)d_in[7];
  const float* gamma_log = (const float*)d_in[8];

  char* ws = (char*)d_ws;
  u16*    x_bf  = (u16*)ws;                                  // 16 MB
  u16*    Bu_bf = (u16*)(ws + ((size_t)16 << 20));           // 32 MB
  u16*    Bcat  = (u16*)(ws + ((size_t)48 << 20));           // 256 KB
  u16*    Ccat  = (u16*)(ws + ((size_t)48 << 20) + 262144);  // 256 KB
  float2* lam   = (float2*)(ws + ((size_t)48 << 20) + 524288);
  float2* lamLC = (float2*)(ws + ((size_t)48 << 20) + 524288 + 4096);
  float2* carry = (float2*)(ws + ((size_t)49 << 20));        // 1 MB
  float2* corr  = (float2*)(ws + ((size_t)50 << 20));        // 1 MB

  prep_kernel<<<2817, 256, 0, stream>>>(x, nu_log, theta_log, B_re, B_im,
                                        C_re, C_im, gamma_log,
                                        x_bf, Bcat, Ccat, lam, lamLC);

  gemm1_kernel<<<dim3(NCAT / 128, L_SEQ / 128), 256, 0, stream>>>(
      x_bf, Bcat, Bu_bf, L_SEQ, NCAT, HDIM);

  scan_carry_kernel<<<NCHUNK, 256, 0, stream>>>((const ushort2*)Bu_bf, lam, carry);

  carry_scan_kernel<<<NDIM, 512, 0, stream>>>(carry, lamLC, corr);

  gemm2_kernel<<<NCHUNK, 256, 0, stream>>>(
      Bu_bf, Ccat, lam, corr, x_bf, Dv, (float*)d_out);
}

// Round 14
// 71.922 us; speedup vs baseline: 1.1395x; 1.0522x over previous
//
#include <hip/hip_runtime.h>

#define L_SEQ 32768
#define NDIM 256
#define HDIM 256
#define NCAT 512   // 2*NDIM (re/im interleaved)
#define LC 64      // scan chunk length
#define NCHUNK 512 // L_SEQ / LC

typedef unsigned short u16;
typedef unsigned int u32;
typedef __bf16 bf16x8 __attribute__((ext_vector_type(8)));
typedef float f32x4 __attribute__((ext_vector_type(4)));
typedef __attribute__((address_space(3))) void lds_void;
typedef const __attribute__((address_space(1))) void gbl_void;

__device__ __forceinline__ u16 f2bf(float f) {
  u32 u = __builtin_bit_cast(u32, f);
  u = u + 0x7fffu + ((u >> 16) & 1u);
  return (u16)(u >> 16);
}
__device__ __forceinline__ float bf2f(u16 v) {
  u32 u = ((u32)v) << 16;
  return __builtin_bit_cast(float, u);
}
__device__ __forceinline__ float2 cmul(float2 a, float2 b) {
  return make_float2(a.x * b.x - a.y * b.y, a.x * b.y + a.y * b.x);
}

// ---------------------------------------------------------------------------
// PREP (R11-verified): x -> bf16 pre-swizzled; Bcat pre-swizzled (BK=64 read);
// Ccat pre-swizzled (BK=32 read, R10 geometry); lambda tables.
// ---------------------------------------------------------------------------
__global__ __launch_bounds__(256) void prep_kernel(
    const float* __restrict__ x,
    const float* __restrict__ nu_log, const float* __restrict__ theta_log,
    const float* __restrict__ B_re, const float* __restrict__ B_im,
    const float* __restrict__ C_re, const float* __restrict__ C_im,
    const float* __restrict__ gamma_log,
    u16* __restrict__ x_bf, u16* __restrict__ Bcat, u16* __restrict__ Ccat,
    float2* __restrict__ lam, float2* __restrict__ lamLC)
{
  const int blk = blockIdx.x, tid = threadIdx.x;
  if (blk < 2048) {
    const float4* src = (const float4*)x;
#pragma unroll
    for (int j = 0; j < 4; ++j) {
      int i = blk * 1024 + j * 256 + tid;
      int r = i >> 6;
      int col = (i & 63) * 4;
      float4 v = src[i];
      int pcol = col ^ ((r & 7) << 3);
      *(ushort4*)(x_bf + (size_t)r * 256 + pcol) =
          make_ushort4(f2bf(v.x), f2bf(v.y), f2bf(v.z), f2bf(v.w));
    }
  } else if (blk < 2560) {
    int pr = blk - 2048;
    int jj = pr >> 1, p = pr & 1;
    float g = expf(gamma_log[jj]);
    const float* src = (p ? B_im : B_re) + (size_t)jj * HDIM;
    int lc = tid ^ ((pr & 7) << 3);
    Bcat[(size_t)pr * HDIM + tid] = f2bf(src[lc] * g);
  } else if (blk < 2816) {
    int ph = blk - 2560;
    int lr = ph ^ ((ph >> 2) & 1);
#pragma unroll
    for (int half = 0; half < 2; ++half) {
      int pcol = half * 256 + tid;
      int kt = pcol >> 5, w = pcol & 31, pc = w >> 3, e = w & 7;
      int lc2 = kt * 32 + (pc ^ (lr & 3)) * 8 + e;
      int jj = lc2 >> 1, p = lc2 & 1;
      float v = p ? -C_im[(size_t)lr * NDIM + jj] : C_re[(size_t)lr * NDIM + jj];
      Ccat[(size_t)ph * NCAT + pcol] = f2bf(v);
    }
  } else {
    float nu_e = expf(nu_log[tid]);
    float th = expf(theta_log[tid]);
    float r = expf(-nu_e);
    lam[tid] = make_float2(r * cosf(th), r * sinf(th));
    float rL = expf(-(float)LC * nu_e);
    float ph = (float)LC * th;
    lamLC[tid] = make_float2(rL * cosf(ph), rL * sinf(ph));
  }
}

// ---------------------------------------------------------------------------
// GEMM1 (R11-verified loop) + register carry epilogue:
// carry[chunk][n] = sum_s lam^{63-s} * Bu[s][n] computed from acc via the
// factorization 63-s = 16(3-i) + (12-4fq) + (3-r); parity lanes combine
// re/im columns; shfl_xor(1/16/32) reduces. No LDS involved.
// ---------------------------------------------------------------------------
__global__ __launch_bounds__(256) void gemm1_kernel(
    const u16* __restrict__ A,   // M x K bf16 (cols pre-swizzled per row)
    const u16* __restrict__ Bm,  // N x K bf16 (cols pre-swizzled per row)
    u16* __restrict__ Cout,      // M x N bf16
    int M, int N, int K,
    const float2* __restrict__ lam,
    float2* __restrict__ carry)  // NCHUNK x NDIM
{
  constexpr int BM = 128, BN = 128, BK = 64;
  __shared__ u16 lA[BM * BK];
  __shared__ u16 lB[BN * BK];
  const int tid = threadIdx.x;
  const int lane = tid & 63, wave = tid >> 6;
  const int bn = blockIdx.x, bm = blockIdx.y;
  const int row0 = bm * BM, col0 = bn * BN;
  const int wm = (wave >> 1) * 64, wn = (wave & 1) * 64;
  const int fr = lane & 15, fq = lane >> 4;
  const int swz = (fr & 7) << 4;
  const char* lab = (const char*)lA;
  const char* lbb = (const char*)lB;

  f32x4 acc[4][4] = {};
  const int nkt = K / BK;  // 4
  for (int kt = 0; kt < nkt; ++kt) {
    const int k0 = kt * BK;
#pragma unroll
    for (int j = 0; j < 4; ++j) {
      int c = j * 256 + tid;
      int r = c >> 3, b = c & 7;
      const u16* ga = A + (size_t)(row0 + r) * K + (k0 + b * 8);
      const u16* gb = Bm + (size_t)(col0 + r) * K + (k0 + b * 8);
      __builtin_amdgcn_global_load_lds((gbl_void*)ga, (lds_void*)&lA[c * 8], 16, 0, 0);
      __builtin_amdgcn_global_load_lds((gbl_void*)gb, (lds_void*)&lB[c * 8], 16, 0, 0);
    }
    __syncthreads();

#pragma unroll
    for (int h = 0; h < 2; ++h) {
      bf16x8 af[4], bfr[4];
      const int ko = (h * 64 + fq * 16) ^ swz;
#pragma unroll
      for (int i = 0; i < 4; ++i) {
        af[i]  = *(const bf16x8*)(lab + (wm + i * 16 + fr) * 128 + ko);
        bfr[i] = *(const bf16x8*)(lbb + (wn + i * 16 + fr) * 128 + ko);
      }
#pragma unroll
      for (int i = 0; i < 4; ++i)
#pragma unroll
        for (int j = 0; j < 4; ++j)
          acc[i][j] = __builtin_amdgcn_mfma_f32_16x16x32_bf16(af[i], bfr[j], acc[i][j], 0, 0, 0);
    }
    __syncthreads();
  }

  // C-write (verified): col = lane&15, row = fq*4 + reg
#pragma unroll
  for (int i = 0; i < 4; ++i)
#pragma unroll
    for (int j = 0; j < 4; ++j) {
      int cg = col0 + wn + j * 16 + fr;
#pragma unroll
      for (int r = 0; r < 4; ++r) {
        int rg = row0 + wm + i * 16 + fq * 4 + r;
        Cout[(size_t)rg * N + cg] = f2bf(acc[i][j][r]);
      }
    }

  // carry epilogue: wave covers chunk 2*bm + (wm>>6), within-chunk row
  // s = i*16 + fq*4 + r; coef = lam^{63-s}
  const int chunk = 2 * bm + (wm >> 6);
#pragma unroll
  for (int j = 0; j < 4; ++j) {
    int cg = col0 + wn + j * 16 + fr;
    float2 L   = lam[cg >> 1];
    float2 L2  = cmul(L, L);
    float2 L3  = cmul(L2, L);
    float2 L4  = cmul(L2, L2);
    float2 L8  = cmul(L4, L4);
    float2 L16 = cmul(L8, L8);
    float2 cBase = (fq == 0) ? cmul(L8, L4)
                 : (fq == 1) ? L8
                 : (fq == 2) ? L4
                 : make_float2(1.f, 0.f);       // lam^{12-4fq}
    float2 cr[4];
    cr[3] = cBase;
    cr[2] = cmul(cBase, L);
    cr[1] = cmul(cBase, L2);
    cr[0] = cmul(cBase, L3);                    // lam^{(12-4fq)+(3-r)}
    float px = 0.f, py = 0.f;
#pragma unroll
    for (int i = 3; i >= 0; --i) {
#pragma unroll
      for (int r = 0; r < 4; ++r) {
        float v = acc[i][j][r];
        px += cr[r].x * v;
        py += cr[r].y * v;
      }
      if (i > 0) {
#pragma unroll
        for (int r = 0; r < 4; ++r) cr[r] = cmul(cr[r], L16);
      }
    }
    // parity combine: even cg (re col) -> (px,py); odd cg (im col) -> (-py,px)
    float cxr = (cg & 1) ? -py : px;
    float cxi = (cg & 1) ?  px : py;
    cxr += __shfl_xor(cxr, 1);
    cxi += __shfl_xor(cxi, 1);
    cxr += __shfl_xor(cxr, 16);
    cxi += __shfl_xor(cxi, 16);
    cxr += __shfl_xor(cxr, 32);
    cxi += __shfl_xor(cxi, 32);
    if ((lane & 49) == 0)  // fq==0 && fr even
      carry[(size_t)chunk * NDIM + (cg >> 1)] = make_float2(cxr, cxi);
  }
}

// ---------------------------------------------------------------------------
// Scan phase 2 (verified): log-depth Hillis-Steele in LDS.
// ---------------------------------------------------------------------------
__global__ __launch_bounds__(512) void carry_scan_kernel(
    const float2* __restrict__ carry, const float2* __restrict__ lamLC,
    float2* __restrict__ corr)
{
  __shared__ float4 e[NCHUNK];
  const int n = blockIdx.x;
  const int b = threadIdx.x;
  float2 a = lamLC[n];
  float2 v = carry[(size_t)b * NDIM + n];
  e[b] = make_float4(a.x, a.y, v.x, v.y);
  __syncthreads();
#pragma unroll
  for (int d = 1; d < NCHUNK; d <<= 1) {
    float4 prev;
    if (b >= d) prev = e[b - d];
    __syncthreads();
    if (b >= d) {
      float2 ap = make_float2(prev.x, prev.y), vp = make_float2(prev.z, prev.w);
      float2 na, nv;
      na.x = a.x * ap.x - a.y * ap.y;
      na.y = a.x * ap.y + a.y * ap.x;
      nv.x = a.x * vp.x - a.y * vp.y + v.x;
      nv.y = a.x * vp.y + a.y * vp.x + v.y;
      a = na; v = nv;
      e[b] = make_float4(a.x, a.y, v.x, v.y);
    }
    __syncthreads();
  }
  if (b == 0) corr[n] = make_float2(0.f, 0.f);
  if (b < NCHUNK - 1) corr[(size_t)(b + 1) * NDIM + n] = v;
}

// ---------------------------------------------------------------------------
// GEMM2 fused (R11-verified, UNCHANGED): one block = one chunk x 256 cols,
// 4 waves, 64x64 per wave; reg-prefetch pipelined k-loop on staged Ccat.
// ---------------------------------------------------------------------------
__global__ __launch_bounds__(256, 2) void gemm2_kernel(
    const u16* __restrict__ Bu,   // L x 512 bf16
    const u16* __restrict__ Cc,   // 256 x 512 bf16 (pre-swizzled)
    const float2* __restrict__ lam,
    const float2* __restrict__ corr,
    const u16* __restrict__ xbf,  // L x 256 bf16 (pre-swizzled cols)
    const float* __restrict__ Dv,
    float* __restrict__ out)      // L x 256 f32
{
  constexpr int BM = 64, BK = 32, K = NCAT; // 16 k-steps
  __shared__ u16 sT[BM * K];      // 64KB: Bu tile -> (swizzled) s tile
  __shared__ u16 lB1[256 * BK];   // 16KB Ccat slice
  const int tid = threadIdx.x;
  const int lane = tid & 63, wave = tid >> 6;
  const int bm = blockIdx.x;
  const int row0 = bm * BM;
  const int wn = wave * 64;
  const int fr = lane & 15, fq = lane >> 4;
  char* sb = (char*)sT;
  const char* cbB = (const char*)lB1;

  // stage Bu tile linear (4096 x 16B) + Ccat slice kt=0 (1024 x 16B)
#pragma unroll
  for (int j = 0; j < 16; ++j) {
    int q = j * 256 + tid;
    int row = q >> 6, off = q & 63;
    const u16* g = Bu + (size_t)(row0 + row) * NCAT + off * 8;
    __builtin_amdgcn_global_load_lds((gbl_void*)g, (lds_void*)&sT[q * 8], 16, 0, 0);
  }
#pragma unroll
  for (int j = 0; j < 4; ++j) {
    int q = j * 256 + tid;
    int row = q >> 2, c = q & 3;
    const u16* g = Cc + (size_t)row * K + c * 8;
    __builtin_amdgcn_global_load_lds((gbl_void*)g, (lds_void*)&lB1[q * 8], 16, 0, 0);
  }
  float2 la = lam[tid];
  float2 c0 = corr[(size_t)bm * NDIM + tid];
  __syncthreads();

  // in-place scan (verified): read linear, write swizzled
  {
    float sre = c0.x, sim = c0.y;
    ushort2 buf[8], nbuf[8];
    const int lb = tid * 4;
#pragma unroll
    for (int s = 0; s < 8; ++s) buf[s] = *(const ushort2*)(sb + s * 1024 + lb);
#pragma unroll
    for (int b8 = 0; b8 < 8; ++b8) {
      if (b8 < 7) {
#pragma unroll
        for (int s = 0; s < 8; ++s)
          nbuf[s] = *(const ushort2*)(sb + (b8 * 8 + 8 + s) * 1024 + lb);
      }
#pragma unroll
      for (int s = 0; s < 8; ++s) {
        int row = b8 * 8 + s;
        float bre = bf2f(buf[s].x), bim = bf2f(buf[s].y);
        float nre = la.x * sre - la.y * sim + bre;
        float nim = la.x * sim + la.y * sre + bim;
        sre = nre; sim = nim;
        *(ushort2*)(sb + row * 1024 + (lb ^ ((row & 7) << 4))) =
            make_ushort2(f2bf(sre), f2bf(sim));
      }
#pragma unroll
      for (int s = 0; s < 8; ++s) buf[s] = nbuf[s];
    }
  }
  __syncthreads();

  // MFMA: 16 k-steps, reg-prefetch pipeline (verified)
  f32x4 acc[4][4] = {};
#pragma unroll 1
  for (int kt = 0; kt < 16; ++kt) {
    bf16x8 af[4], bfr[4];
#pragma unroll
    for (int j = 0; j < 4; ++j) {
      int rowb = wn + j * 16 + fr;
      bfr[j] = *(const bf16x8*)(cbB + ((rowb * 64 + fq * 16) ^ ((rowb & 7) << 4)));
    }
#pragma unroll
    for (int i = 0; i < 4; ++i) {
      int row = i * 16 + fr;
      int wb = kt * 64 + fq * 16;
      af[i] = *(const bf16x8*)(sb + row * 1024 + (wb ^ ((row & 7) << 4)));
    }
    __syncthreads();
    __builtin_amdgcn_sched_barrier(0);
    if (kt < 15) {
#pragma unroll
      for (int j = 0; j < 4; ++j) {
        int q = j * 256 + tid;
        int row = q >> 2, c = q & 3;
        const u16* g = Cc + (size_t)row * K + (kt + 1) * BK + c * 8;
        __builtin_amdgcn_global_load_lds((gbl_void*)g, (lds_void*)&lB1[q * 8], 16, 0, 0);
      }
    }
    __builtin_amdgcn_sched_barrier(0);
#pragma unroll
    for (int i = 0; i < 4; ++i)
#pragma unroll
      for (int j = 0; j < 4; ++j)
        acc[i][j] = __builtin_amdgcn_mfma_f32_16x16x32_bf16(af[i], bfr[j], acc[i][j], 0, 0, 0);
    __syncthreads();
  }

  // epilogue: y = acc + x*D (xbf cols pre-swizzled: c -> c ^ ((r&7)<<3))
#pragma unroll
  for (int i = 0; i < 4; ++i)
#pragma unroll
    for (int j = 0; j < 4; ++j) {
      int cg = wn + j * 16 + fr;
      float dvc = Dv[cg];
#pragma unroll
      for (int r = 0; r < 4; ++r) {
        int rg = row0 + i * 16 + fq * 4 + r;
        float v = acc[i][j][r] +
                  bf2f(xbf[(size_t)rg * HDIM + (cg ^ ((rg & 7) << 3))]) * dvc;
        out[(size_t)rg * HDIM + cg] = v;
      }
    }
}

// ---------------------------------------------------------------------------
extern "C" void kernel_launch(void* const* d_in, const int* in_sizes, int n_in,
                              void* d_out, int out_size, void* d_ws, size_t ws_size,
                              hipStream_t stream)
{
  (void)in_sizes; (void)n_in; (void)out_size; (void)ws_size;
  const float* x         = (const float*)d_in[0];
  const float* nu_log    = (const float*)d_in[1];
  const float* theta_log = (const float*)d_in[2];
  const float* B_re      = (const float*)d_in[3];
  const float* B_im      = (const float*)d_in[4];
  const float* C_re      = (const float*)d_in[5];
  const float* C_im      = (const float*)d_in[6];
  const float* Dv        = (const float*)d_in[7];
  const float* gamma_log = (const float*)d_in[8];

  char* ws = (char*)d_ws;
  u16*    x_bf  = (u16*)ws;                                  // 16 MB
  u16*    Bu_bf = (u16*)(ws + ((size_t)16 << 20));           // 32 MB
  u16*    Bcat  = (u16*)(ws + ((size_t)48 << 20));           // 256 KB
  u16*    Ccat  = (u16*)(ws + ((size_t)48 << 20) + 262144);  // 256 KB
  float2* lam   = (float2*)(ws + ((size_t)48 << 20) + 524288);
  float2* lamLC = (float2*)(ws + ((size_t)48 << 20) + 524288 + 4096);
  float2* carry = (float2*)(ws + ((size_t)49 << 20));        // 1 MB
  float2* corr  = (float2*)(ws + ((size_t)50 << 20));        // 1 MB

  prep_kernel<<<2817, 256, 0, stream>>>(x, nu_log, theta_log, B_re, B_im,
                                        C_re, C_im, gamma_log,
                                        x_bf, Bcat, Ccat, lam, lamLC);

  gemm1_kernel<<<dim3(NCAT / 128, L_SEQ / 128), 256, 0, stream>>>(
      x_bf, Bcat, Bu_bf, L_SEQ, NCAT, HDIM, lam, carry);

  carry_scan_kernel<<<NDIM, 512, 0, stream>>>(carry, lamLC, corr);

  gemm2_kernel<<<NCHUNK, 256, 0, stream>>>(
      Bu_bf, Ccat, lam, corr, x_bf, Dv, (float*)d_out);
}

// Round 15
// 69.255 us; speedup vs baseline: 1.1834x; 1.0385x over previous
//
#include <hip/hip_runtime.h>

#define L_SEQ 32768
#define NDIM 256
#define HDIM 256
#define NCAT 512   // 2*NDIM (re/im interleaved)
#define LC 64      // scan chunk length
#define NCHUNK 512 // L_SEQ / LC

typedef unsigned short u16;
typedef unsigned int u32;
typedef __bf16 bf16x8 __attribute__((ext_vector_type(8)));
typedef float f32x4 __attribute__((ext_vector_type(4)));
typedef __attribute__((address_space(3))) void lds_void;
typedef const __attribute__((address_space(1))) void gbl_void;

__device__ __forceinline__ u16 f2bf(float f) {
  u32 u = __builtin_bit_cast(u32, f);
  u = u + 0x7fffu + ((u >> 16) & 1u);
  return (u16)(u >> 16);
}
__device__ __forceinline__ float bf2f(u16 v) {
  u32 u = ((u32)v) << 16;
  return __builtin_bit_cast(float, u);
}
__device__ __forceinline__ float2 cmul(float2 a, float2 b) {
  return make_float2(a.x * b.x - a.y * b.y, a.x * b.y + a.y * b.x);
}

// ---------------------------------------------------------------------------
// PREP (R11-verified): x -> bf16 pre-swizzled; Bcat pre-swizzled (BK=64 read);
// Ccat pre-swizzled (BK=32 read, R10 geometry); lambda tables.
// ---------------------------------------------------------------------------
__global__ __launch_bounds__(256) void prep_kernel(
    const float* __restrict__ x,
    const float* __restrict__ nu_log, const float* __restrict__ theta_log,
    const float* __restrict__ B_re, const float* __restrict__ B_im,
    const float* __restrict__ C_re, const float* __restrict__ C_im,
    const float* __restrict__ gamma_log,
    u16* __restrict__ x_bf, u16* __restrict__ Bcat, u16* __restrict__ Ccat,
    float2* __restrict__ lam, float2* __restrict__ lamLC)
{
  const int blk = blockIdx.x, tid = threadIdx.x;
  if (blk < 2048) {
    const float4* src = (const float4*)x;
#pragma unroll
    for (int j = 0; j < 4; ++j) {
      int i = blk * 1024 + j * 256 + tid;
      int r = i >> 6;
      int col = (i & 63) * 4;
      float4 v = src[i];
      int pcol = col ^ ((r & 7) << 3);
      *(ushort4*)(x_bf + (size_t)r * 256 + pcol) =
          make_ushort4(f2bf(v.x), f2bf(v.y), f2bf(v.z), f2bf(v.w));
    }
  } else if (blk < 2560) {
    int pr = blk - 2048;
    int jj = pr >> 1, p = pr & 1;
    float g = expf(gamma_log[jj]);
    const float* src = (p ? B_im : B_re) + (size_t)jj * HDIM;
    int lc = tid ^ ((pr & 7) << 3);
    Bcat[(size_t)pr * HDIM + tid] = f2bf(src[lc] * g);
  } else if (blk < 2816) {
    int ph = blk - 2560;
    int lr = ph ^ ((ph >> 2) & 1);
#pragma unroll
    for (int half = 0; half < 2; ++half) {
      int pcol = half * 256 + tid;
      int kt = pcol >> 5, w = pcol & 31, pc = w >> 3, e = w & 7;
      int lc2 = kt * 32 + (pc ^ (lr & 3)) * 8 + e;
      int jj = lc2 >> 1, p = lc2 & 1;
      float v = p ? -C_im[(size_t)lr * NDIM + jj] : C_re[(size_t)lr * NDIM + jj];
      Ccat[(size_t)ph * NCAT + pcol] = f2bf(v);
    }
  } else {
    float nu_e = expf(nu_log[tid]);
    float th = expf(theta_log[tid]);
    float r = expf(-nu_e);
    lam[tid] = make_float2(r * cosf(th), r * sinf(th));
    float rL = expf(-(float)LC * nu_e);
    float ph = (float)LC * th;
    lamLC[tid] = make_float2(rL * cosf(ph), rL * sinf(ph));
  }
}

// ---------------------------------------------------------------------------
// GEMM1 (R14-verified) + XCD-aware block swizzle: logical id
// lid = (bid%8)*128 + bid/8 over a flat 1024-grid; bn = lid&3, bm = lid>>2.
// XCD k owns rows [k*4096,(k+1)*4096) -- same partition as gemm2's chunks,
// so A-tiles are XCD-local and Bu is produced into the consuming XCD's L2.
// Register carry epilogue (R14-verified).
// ---------------------------------------------------------------------------
__global__ __launch_bounds__(256) void gemm1_kernel(
    const u16* __restrict__ A,   // M x K bf16 (cols pre-swizzled per row)
    const u16* __restrict__ Bm,  // N x K bf16 (cols pre-swizzled per row)
    u16* __restrict__ Cout,      // M x N bf16
    int M, int N, int K,
    const float2* __restrict__ lam,
    float2* __restrict__ carry)  // NCHUNK x NDIM
{
  constexpr int BM = 128, BN = 128, BK = 64;
  __shared__ u16 lA[BM * BK];
  __shared__ u16 lB[BN * BK];
  const int tid = threadIdx.x;
  const int lane = tid & 63, wave = tid >> 6;
  const int lid = (blockIdx.x & 7) * 128 + (blockIdx.x >> 3);
  const int bn = lid & 3, bm = lid >> 2;
  const int row0 = bm * BM, col0 = bn * BN;
  const int wm = (wave >> 1) * 64, wn = (wave & 1) * 64;
  const int fr = lane & 15, fq = lane >> 4;
  const int swz = (fr & 7) << 4;
  const char* lab = (const char*)lA;
  const char* lbb = (const char*)lB;

  f32x4 acc[4][4] = {};
  const int nkt = K / BK;  // 4
  for (int kt = 0; kt < nkt; ++kt) {
    const int k0 = kt * BK;
#pragma unroll
    for (int j = 0; j < 4; ++j) {
      int c = j * 256 + tid;
      int r = c >> 3, b = c & 7;
      const u16* ga = A + (size_t)(row0 + r) * K + (k0 + b * 8);
      const u16* gb = Bm + (size_t)(col0 + r) * K + (k0 + b * 8);
      __builtin_amdgcn_global_load_lds((gbl_void*)ga, (lds_void*)&lA[c * 8], 16, 0, 0);
      __builtin_amdgcn_global_load_lds((gbl_void*)gb, (lds_void*)&lB[c * 8], 16, 0, 0);
    }
    __syncthreads();

#pragma unroll
    for (int h = 0; h < 2; ++h) {
      bf16x8 af[4], bfr[4];
      const int ko = (h * 64 + fq * 16) ^ swz;
#pragma unroll
      for (int i = 0; i < 4; ++i) {
        af[i]  = *(const bf16x8*)(lab + (wm + i * 16 + fr) * 128 + ko);
        bfr[i] = *(const bf16x8*)(lbb + (wn + i * 16 + fr) * 128 + ko);
      }
#pragma unroll
      for (int i = 0; i < 4; ++i)
#pragma unroll
        for (int j = 0; j < 4; ++j)
          acc[i][j] = __builtin_amdgcn_mfma_f32_16x16x32_bf16(af[i], bfr[j], acc[i][j], 0, 0, 0);
    }
    __syncthreads();
  }

  // C-write (verified): col = lane&15, row = fq*4 + reg
#pragma unroll
  for (int i = 0; i < 4; ++i)
#pragma unroll
    for (int j = 0; j < 4; ++j) {
      int cg = col0 + wn + j * 16 + fr;
#pragma unroll
      for (int r = 0; r < 4; ++r) {
        int rg = row0 + wm + i * 16 + fq * 4 + r;
        Cout[(size_t)rg * N + cg] = f2bf(acc[i][j][r]);
      }
    }

  // carry epilogue (R14-verified): coef = lam^{63-s}, s = i*16 + fq*4 + r
  const int chunk = 2 * bm + (wm >> 6);
#pragma unroll
  for (int j = 0; j < 4; ++j) {
    int cg = col0 + wn + j * 16 + fr;
    float2 L   = lam[cg >> 1];
    float2 L2  = cmul(L, L);
    float2 L3  = cmul(L2, L);
    float2 L4  = cmul(L2, L2);
    float2 L8  = cmul(L4, L4);
    float2 L16 = cmul(L8, L8);
    float2 cBase = (fq == 0) ? cmul(L8, L4)
                 : (fq == 1) ? L8
                 : (fq == 2) ? L4
                 : make_float2(1.f, 0.f);       // lam^{12-4fq}
    float2 cr[4];
    cr[3] = cBase;
    cr[2] = cmul(cBase, L);
    cr[1] = cmul(cBase, L2);
    cr[0] = cmul(cBase, L3);                    // lam^{(12-4fq)+(3-r)}
    float px = 0.f, py = 0.f;
#pragma unroll
    for (int i = 3; i >= 0; --i) {
#pragma unroll
      for (int r = 0; r < 4; ++r) {
        float v = acc[i][j][r];
        px += cr[r].x * v;
        py += cr[r].y * v;
      }
      if (i > 0) {
#pragma unroll
        for (int r = 0; r < 4; ++r) cr[r] = cmul(cr[r], L16);
      }
    }
    float cxr = (cg & 1) ? -py : px;
    float cxi = (cg & 1) ?  px : py;
    cxr += __shfl_xor(cxr, 1);
    cxi += __shfl_xor(cxi, 1);
    cxr += __shfl_xor(cxr, 16);
    cxi += __shfl_xor(cxi, 16);
    cxr += __shfl_xor(cxr, 32);
    cxi += __shfl_xor(cxi, 32);
    if ((lane & 49) == 0)  // fq==0 && fr even
      carry[(size_t)chunk * NDIM + (cg >> 1)] = make_float2(cxr, cxi);
  }
}

// ---------------------------------------------------------------------------
// Scan phase 2 (verified): log-depth Hillis-Steele in LDS.
// ---------------------------------------------------------------------------
__global__ __launch_bounds__(512) void carry_scan_kernel(
    const float2* __restrict__ carry, const float2* __restrict__ lamLC,
    float2* __restrict__ corr)
{
  __shared__ float4 e[NCHUNK];
  const int n = blockIdx.x;
  const int b = threadIdx.x;
  float2 a = lamLC[n];
  float2 v = carry[(size_t)b * NDIM + n];
  e[b] = make_float4(a.x, a.y, v.x, v.y);
  __syncthreads();
#pragma unroll
  for (int d = 1; d < NCHUNK; d <<= 1) {
    float4 prev;
    if (b >= d) prev = e[b - d];
    __syncthreads();
    if (b >= d) {
      float2 ap = make_float2(prev.x, prev.y), vp = make_float2(prev.z, prev.w);
      float2 na, nv;
      na.x = a.x * ap.x - a.y * ap.y;
      na.y = a.x * ap.y + a.y * ap.x;
      nv.x = a.x * vp.x - a.y * vp.y + v.x;
      nv.y = a.x * vp.y + a.y * vp.x + v.y;
      a = na; v = nv;
      e[b] = make_float4(a.x, a.y, v.x, v.y);
    }
    __syncthreads();
  }
  if (b == 0) corr[n] = make_float2(0.f, 0.f);
  if (b < NCHUNK - 1) corr[(size_t)(b + 1) * NDIM + n] = v;
}

// ---------------------------------------------------------------------------
// GEMM2 fused (R11-verified) + XCD-aware swizzle: bm = (bid%8)*64 + bid/8.
// XCD k owns chunks [k*64,(k+1)*64) = rows [k*4096,(k+1)*4096) -- the same
// rows gemm1 produced on XCD k, so Bu reads hit the local L2.
// ---------------------------------------------------------------------------
__global__ __launch_bounds__(256, 2) void gemm2_kernel(
    const u16* __restrict__ Bu,   // L x 512 bf16
    const u16* __restrict__ Cc,   // 256 x 512 bf16 (pre-swizzled)
    const float2* __restrict__ lam,
    const float2* __restrict__ corr,
    const u16* __restrict__ xbf,  // L x 256 bf16 (pre-swizzled cols)
    const float* __restrict__ Dv,
    float* __restrict__ out)      // L x 256 f32
{
  constexpr int BM = 64, BK = 32, K = NCAT; // 16 k-steps
  __shared__ u16 sT[BM * K];      // 64KB: Bu tile -> (swizzled) s tile
  __shared__ u16 lB1[256 * BK];   // 16KB Ccat slice
  const int tid = threadIdx.x;
  const int lane = tid & 63, wave = tid >> 6;
  const int bm = (blockIdx.x & 7) * 64 + (blockIdx.x >> 3);
  const int row0 = bm * BM;
  const int wn = wave * 64;
  const int fr = lane & 15, fq = lane >> 4;
  char* sb = (char*)sT;
  const char* cbB = (const char*)lB1;

  // stage Bu tile linear (4096 x 16B) + Ccat slice kt=0 (1024 x 16B)
#pragma unroll
  for (int j = 0; j < 16; ++j) {
    int q = j * 256 + tid;
    int row = q >> 6, off = q & 63;
    const u16* g = Bu + (size_t)(row0 + row) * NCAT + off * 8;
    __builtin_amdgcn_global_load_lds((gbl_void*)g, (lds_void*)&sT[q * 8], 16, 0, 0);
  }
#pragma unroll
  for (int j = 0; j < 4; ++j) {
    int q = j * 256 + tid;
    int row = q >> 2, c = q & 3;
    const u16* g = Cc + (size_t)row * K + c * 8;
    __builtin_amdgcn_global_load_lds((gbl_void*)g, (lds_void*)&lB1[q * 8], 16, 0, 0);
  }
  float2 la = lam[tid];
  float2 c0 = corr[(size_t)bm * NDIM + tid];
  __syncthreads();

  // in-place scan (verified): read linear, write swizzled
  {
    float sre = c0.x, sim = c0.y;
    ushort2 buf[8], nbuf[8];
    const int lb = tid * 4;
#pragma unroll
    for (int s = 0; s < 8; ++s) buf[s] = *(const ushort2*)(sb + s * 1024 + lb);
#pragma unroll
    for (int b8 = 0; b8 < 8; ++b8) {
      if (b8 < 7) {
#pragma unroll
        for (int s = 0; s < 8; ++s)
          nbuf[s] = *(const ushort2*)(sb + (b8 * 8 + 8 + s) * 1024 + lb);
      }
#pragma unroll
      for (int s = 0; s < 8; ++s) {
        int row = b8 * 8 + s;
        float bre = bf2f(buf[s].x), bim = bf2f(buf[s].y);
        float nre = la.x * sre - la.y * sim + bre;
        float nim = la.x * sim + la.y * sre + bim;
        sre = nre; sim = nim;
        *(ushort2*)(sb + row * 1024 + (lb ^ ((row & 7) << 4))) =
            make_ushort2(f2bf(sre), f2bf(sim));
      }
#pragma unroll
      for (int s = 0; s < 8; ++s) buf[s] = nbuf[s];
    }
  }
  __syncthreads();

  // MFMA: 16 k-steps, reg-prefetch pipeline (verified)
  f32x4 acc[4][4] = {};
#pragma unroll 1
  for (int kt = 0; kt < 16; ++kt) {
    bf16x8 af[4], bfr[4];
#pragma unroll
    for (int j = 0; j < 4; ++j) {
      int rowb = wn + j * 16 + fr;
      bfr[j] = *(const bf16x8*)(cbB + ((rowb * 64 + fq * 16) ^ ((rowb & 7) << 4)));
    }
#pragma unroll
    for (int i = 0; i < 4; ++i) {
      int row = i * 16 + fr;
      int wb = kt * 64 + fq * 16;
      af[i] = *(const bf16x8*)(sb + row * 1024 + (wb ^ ((row & 7) << 4)));
    }
    __syncthreads();
    __builtin_amdgcn_sched_barrier(0);
    if (kt < 15) {
#pragma unroll
      for (int j = 0; j < 4; ++j) {
        int q = j * 256 + tid;
        int row = q >> 2, c = q & 3;
        const u16* g = Cc + (size_t)row * K + (kt + 1) * BK + c * 8;
        __builtin_amdgcn_global_load_lds((gbl_void*)g, (lds_void*)&lB1[q * 8], 16, 0, 0);
      }
    }
    __builtin_amdgcn_sched_barrier(0);
#pragma unroll
    for (int i = 0; i < 4; ++i)
#pragma unroll
      for (int j = 0; j < 4; ++j)
        acc[i][j] = __builtin_amdgcn_mfma_f32_16x16x32_bf16(af[i], bfr[j], acc[i][j], 0, 0, 0);
    __syncthreads();
  }

  // epilogue: y = acc + x*D (xbf cols pre-swizzled: c -> c ^ ((r&7)<<3))
#pragma unroll
  for (int i = 0; i < 4; ++i)
#pragma unroll
    for (int j = 0; j < 4; ++j) {
      int cg = wn + j * 16 + fr;
      float dvc = Dv[cg];
#pragma unroll
      for (int r = 0; r < 4; ++r) {
        int rg = row0 + i * 16 + fq * 4 + r;
        float v = acc[i][j][r] +
                  bf2f(xbf[(size_t)rg * HDIM + (cg ^ ((rg & 7) << 3))]) * dvc;
        out[(size_t)rg * HDIM + cg] = v;
      }
    }
}

// ---------------------------------------------------------------------------
extern "C" void kernel_launch(void* const* d_in, const int* in_sizes, int n_in,
                              void* d_out, int out_size, void* d_ws, size_t ws_size,
                              hipStream_t stream)
{
  (void)in_sizes; (void)n_in; (void)out_size; (void)ws_size;
  const float* x         = (const float*)d_in[0];
  const float* nu_log    = (const float*)d_in[1];
  const float* theta_log = (const float*)d_in[2];
  const float* B_re      = (const float*)d_in[3];
  const float* B_im      = (const float*)d_in[4];
  const float* C_re      = (const float*)d_in[5];
  const float* C_im      = (const float*)d_in[6];
  const float* Dv        = (const float*)d_in[7];
  const float* gamma_log = (const float*)d_in[8];

  char* ws = (char*)d_ws;
  u16*    x_bf  = (u16*)ws;                                  // 16 MB
  u16*    Bu_bf = (u16*)(ws + ((size_t)16 << 20));           // 32 MB
  u16*    Bcat  = (u16*)(ws + ((size_t)48 << 20));           // 256 KB
  u16*    Ccat  = (u16*)(ws + ((size_t)48 << 20) + 262144);  // 256 KB
  float2* lam   = (float2*)(ws + ((size_t)48 << 20) + 524288);
  float2* lamLC = (float2*)(ws + ((size_t)48 << 20) + 524288 + 4096);
  float2* carry = (float2*)(ws + ((size_t)49 << 20));        // 1 MB
  float2* corr  = (float2*)(ws + ((size_t)50 << 20));        // 1 MB

  prep_kernel<<<2817, 256, 0, stream>>>(x, nu_log, theta_log, B_re, B_im,
                                        C_re, C_im, gamma_log,
                                        x_bf, Bcat, Ccat, lam, lamLC);

  gemm1_kernel<<<1024, 256, 0, stream>>>(
      x_bf, Bcat, Bu_bf, L_SEQ, NCAT, HDIM, lam, carry);

  carry_scan_kernel<<<NDIM, 512, 0, stream>>>(carry, lamLC, corr);

  gemm2_kernel<<<NCHUNK, 256, 0, stream>>>(
      Bu_bf, Ccat, lam, corr, x_bf, Dv, (float*)d_out);
}